// Round 1
// baseline (376.169 us; speedup 1.0000x reference)
//
#include <hip/hip_runtime.h>
#include <hip/hip_fp16.h>
#include <stdint.h>

#define B_ 32
#define T_ 4096
#define P_ 512
#define W_ 128
#define NMEL 80
#define FILT 256
#define PDIM 64
#define KW 9
#define TP8 (T_ + 8)
#define MSTR 104
#define YSTR 264
#define EPS 1e-5f

typedef unsigned short u16;
typedef __attribute__((ext_vector_type(8))) short short8;
typedef __attribute__((ext_vector_type(4))) float f32x4;

typedef const __attribute__((address_space(1))) uint32_t* gptr_t;
typedef __attribute__((address_space(3))) uint32_t* lptr_t;

__device__ __forceinline__ u16 f2h(float v){ return __half_as_ushort(__float2half(v)); }

#define MFMA16(accv, av, bv) \
  asm volatile("v_mfma_f32_16x16x32_f16 %0, %1, %2, %0" : "+v"(accv) : "v"(av), "v"(bv))

// ---------------- prep: pack conv weights to [tap][kg][cout][8] fp16 ----------------
__global__ void pack_w(const float* __restrict__ w1, const float* __restrict__ w2,
                       u16* __restrict__ Wp1, u16* __restrict__ Wp2){
  int i = blockIdx.x * 256 + threadIdx.x;
  const int N1 = KW * 12 * FILT;          // 27648
  const int N2 = KW * 32 * FILT;          // 73728
  if (i < N1){
    int tap = i / (12*FILT); int r = i - tap*12*FILT; int kg = r / FILT; int co = r - kg*FILT;
    short8 v;
    #pragma unroll
    for (int e=0;e<8;e++){
      int ci = kg*8 + e;
      float x = (ci < NMEL) ? w1[(co*NMEL + ci)*KW + tap] : 0.f;
      v[e] = (short)f2h(x);
    }
    *(short8*)(Wp1 + (size_t)i*8) = v;
  } else if (i < N1 + N2){
    int j = i - N1;
    int tap = j / (32*FILT); int r = j - tap*32*FILT; int kg = r / FILT; int co = r - kg*FILT;
    short8 v;
    #pragma unroll
    for (int e=0;e<8;e++){
      int ci = kg*8 + e;
      v[e] = (short)f2h(w2[(co*FILT + ci)*KW + tap]);
    }
    *(short8*)(Wp2 + (size_t)j*8) = v;
  }
}

// ---------------- prep: mels -> padded fp16 [B][T+8][104] ----------------
__global__ void prep_mels(const float* __restrict__ mels, u16* __restrict__ melsPad){
  int idx = blockIdx.x * 256 + threadIdx.x;
  if (idx >= B_*TP8*MSTR) return;
  int c = idx % MSTR; int r = idx / MSTR; int row = r % TP8; int b = r / TP8;
  float v = 0.f;
  int t = row - 4;
  if (t >= 0 && t < T_ && c < NMEL) v = mels[((size_t)b*T_ + t)*NMEL + c];
  melsPad[idx] = f2h(v);
}

// ---------------- prep: cumsums, frame->phone, phone->word, zero y1 halos ----------------
__global__ void prep_seg(const int* __restrict__ dur, const int* __restrict__ wpl,
                         int* __restrict__ dcum, int* __restrict__ wcum,
                         int* __restrict__ pid, int* __restrict__ wid,
                         u16* __restrict__ y1Pad){
  int b = blockIdx.x; int tid = threadIdx.x;
  __shared__ int dc[P_];
  __shared__ int wc[W_];
  if (tid == 0){ int run=0; for (int p=0;p<P_;p++){ run += dur[b*P_+p]; dc[p]=run; dcum[b*P_+p]=run; } }
  if (tid == 1){ int run=0; for (int w=0;w<W_;w++){ run += wpl[b*W_+w]; wc[w]=run; wcum[b*W_+w]=run; } }
  __syncthreads();
  for (int t=tid; t<T_; t+=256){
    int lo=0, hi=P_;
    while (lo < hi){ int mid=(lo+hi)>>1; if (dc[mid] > t) hi=mid; else lo=mid+1; }
    pid[b*T_+t] = lo;                 // may be P_ if t beyond total (dropped later)
  }
  for (int p=tid; p<P_; p+=256){
    int lo=0, hi=W_;
    while (lo < hi){ int mid=(lo+hi)>>1; if (wc[mid] > p) hi=mid; else lo=mid+1; }
    wid[b*P_+p] = min(lo, W_-1);
  }
  for (int i=tid; i<8*YSTR; i+=256){
    int rr = i / YSTR; int cc = i - rr*YSTR;
    int row = (rr < 4) ? rr : (T_ + rr);   // rows 0..3 and T_+4..T_+7
    y1Pad[((size_t)b*TP8 + row)*YSTR + cc] = 0;
  }
}

// ---------------- conv1 + bias + relu + LN1 -> y1Pad fp16 ----------------
__global__ __launch_bounds__(256, 2) void conv1_k(
    const u16* __restrict__ melsPad, const u16* __restrict__ Wp1,
    const float* __restrict__ bias, const float* __restrict__ lng,
    const float* __restrict__ lnb, u16* __restrict__ y1Pad){
  __shared__ __align__(16) u16 sA[14336];   // 28672 B: 136 rows x 104
  __shared__ __align__(16) u16 sB[24576];   // 49152 B: 12 kg x 256 x 8
  const int tid = threadIdx.x;
  const int wave = tid >> 6, lane = tid & 63, lo = lane & 15, hi = lane >> 4;
  const int b = blockIdx.y, t0 = blockIdx.x * 128;

  {
    const char* gsrc = (const char*)(melsPad + ((size_t)b*TP8 + t0)*MSTR);
    #pragma unroll
    for (int it=0; it<7; ++it)
      __builtin_amdgcn_global_load_lds((gptr_t)(gsrc + it*4096 + tid*16),
                                       (lptr_t)((char*)sA + it*4096 + (wave<<10)), 16, 0, 0);
  }

  f32x4 acc[8][4];
  #pragma unroll
  for (int m=0;m<8;m++)
    #pragma unroll
    for (int n=0;n<4;n++) acc[m][n] = (f32x4){0.f,0.f,0.f,0.f};

  for (int tap=0; tap<KW; ++tap){
    __syncthreads();
    {
      const char* gsrc = (const char*)(Wp1 + (size_t)tap*12*FILT*8);
      #pragma unroll
      for (int it=0; it<12; ++it)
        __builtin_amdgcn_global_load_lds((gptr_t)(gsrc + it*4096 + tid*16),
                                         (lptr_t)((char*)sB + it*4096 + (wave<<10)), 16, 0, 0);
    }
    __syncthreads();
    #pragma unroll
    for (int s=0;s<3;++s){
      short8 av[8], wv[4];
      #pragma unroll
      for (int m=0;m<8;m++)
        av[m] = *(const short8*)(sA + (m*16 + lo + tap)*MSTR + s*32 + hi*8);
      #pragma unroll
      for (int n=0;n<4;n++)
        wv[n] = *(const short8*)(sB + ((s*4 + hi)*FILT + wave*64 + n*16 + lo)*8);
      #pragma unroll
      for (int m=0;m<8;m++)
        #pragma unroll
        for (int n=0;n<4;n++)
          MFMA16(acc[m][n], av[m], wv[n]);
    }
  }
  asm volatile("s_nop 7\n\ts_nop 7" :: );
  __syncthreads();

  float* sred  = (float*)sB;     // [128][4]
  float* sred2 = sred + 512;     // [128][4]
  float* smean = sred2 + 512;    // [128]
  float* srstd = smean + 128;    // [128]

  float bcol[4], gcol[4], btcol[4];
  #pragma unroll
  for (int n=0;n<4;n++){
    int c = wave*64 + n*16 + lo;
    bcol[n]=bias[c]; gcol[n]=lng[c]; btcol[n]=lnb[c];
  }
  #pragma unroll
  for (int m=0;m<8;m++){
    #pragma unroll
    for (int jj=0;jj<4;jj++){
      float s=0.f, q=0.f;
      #pragma unroll
      for (int n=0;n<4;n++){
        float v = fmaxf(acc[m][n][jj] + bcol[n], 0.f);
        s += v; q += v*v;
      }
      #pragma unroll
      for (int off=1; off<16; off<<=1){ s += __shfl_xor(s, off); q += __shfl_xor(q, off); }
      if (lo == 0){ int r = m*16 + hi*4 + jj; sred[r*4+wave] = s; sred2[r*4+wave] = q; }
    }
  }
  __syncthreads();
  if (tid < 128){
    float ss=0.f, qq=0.f;
    #pragma unroll
    for (int w2=0; w2<4; w2++){ ss += sred[tid*4+w2]; qq += sred2[tid*4+w2]; }
    float mean = ss * (1.f/FILT);
    float var  = qq * (1.f/FILT) - mean*mean;
    smean[tid] = mean;
    srstd[tid] = rsqrtf(fmaxf(var, 0.f) + EPS);
  }
  __syncthreads();
  #pragma unroll
  for (int m=0;m<8;m++){
    float mn[4], rs[4];
    #pragma unroll
    for (int jj=0;jj<4;jj++){ int r = m*16+hi*4+jj; mn[jj]=smean[r]; rs[jj]=srstd[r]; }
    #pragma unroll
    for (int jj=0;jj<4;jj++){
      int r = m*16 + hi*4 + jj;
      #pragma unroll
      for (int n=0;n<4;n++){
        float v = fmaxf(acc[m][n][jj] + bcol[n], 0.f);
        float o = (v - mn[jj])*rs[jj]*gcol[n] + btcol[n];
        y1Pad[((size_t)b*TP8 + 4 + t0 + r)*YSTR + wave*64 + n*16 + lo] = f2h(o);
      }
    }
  }
}

// ---------------- conv2 + bias + relu + LN2 -> phone-sum atomics ----------------
__global__ __launch_bounds__(256, 1) void conv2_k(
    const u16* __restrict__ y1Pad, const u16* __restrict__ Wp2,
    const float* __restrict__ bias, const float* __restrict__ lng,
    const float* __restrict__ lnb, const int* __restrict__ pid,
    float* __restrict__ ps){
  __shared__ __align__(16) u16 sA[36864];   // 73728 B: 136 rows x 264
  __shared__ __align__(16) u16 sB[32768];   // 65536 B: 16 kg x 256 x 8
  __shared__ int pidT[128];
  const int tid = threadIdx.x;
  const int wave = tid >> 6, lane = tid & 63, lo = lane & 15, hi = lane >> 4;
  const int b = blockIdx.y, t0 = blockIdx.x * 128;

  if (tid < 128) pidT[tid] = pid[b*T_ + t0 + tid];
  {
    const char* gsrc = (const char*)(y1Pad + ((size_t)b*TP8 + t0)*YSTR);
    #pragma unroll
    for (int it=0; it<18; ++it)
      __builtin_amdgcn_global_load_lds((gptr_t)(gsrc + it*4096 + tid*16),
                                       (lptr_t)((char*)sA + it*4096 + (wave<<10)), 16, 0, 0);
  }

  f32x4 acc[8][4];
  #pragma unroll
  for (int m=0;m<8;m++)
    #pragma unroll
    for (int n=0;n<4;n++) acc[m][n] = (f32x4){0.f,0.f,0.f,0.f};

  for (int tap=0; tap<KW; ++tap){
    for (int half=0; half<2; ++half){
      __syncthreads();
      {
        const char* gsrc = (const char*)(Wp2 + ((size_t)(tap*32 + half*16))*FILT*8);
        #pragma unroll
        for (int it=0; it<16; ++it)
          __builtin_amdgcn_global_load_lds((gptr_t)(gsrc + it*4096 + tid*16),
                                           (lptr_t)((char*)sB + it*4096 + (wave<<10)), 16, 0, 0);
      }
      __syncthreads();
      #pragma unroll
      for (int s=0;s<4;++s){
        short8 av[8], wv[4];
        #pragma unroll
        for (int m=0;m<8;m++)
          av[m] = *(const short8*)(sA + (m*16 + lo + tap)*YSTR + half*128 + s*32 + hi*8);
        #pragma unroll
        for (int n=0;n<4;n++)
          wv[n] = *(const short8*)(sB + ((s*4 + hi)*FILT + wave*64 + n*16 + lo)*8);
        #pragma unroll
        for (int m=0;m<8;m++)
          #pragma unroll
          for (int n=0;n<4;n++)
            MFMA16(acc[m][n], av[m], wv[n]);
      }
    }
  }
  asm volatile("s_nop 7\n\ts_nop 7" :: );
  __syncthreads();

  float* sred  = (float*)sB;
  float* sred2 = sred + 512;
  float* smean = sred2 + 512;
  float* srstd = smean + 128;

  float bcol[4], gcol[4], btcol[4];
  #pragma unroll
  for (int n=0;n<4;n++){
    int c = wave*64 + n*16 + lo;
    bcol[n]=bias[c]; gcol[n]=lng[c]; btcol[n]=lnb[c];
  }
  #pragma unroll
  for (int m=0;m<8;m++){
    #pragma unroll
    for (int jj=0;jj<4;jj++){
      float s=0.f, q=0.f;
      #pragma unroll
      for (int n=0;n<4;n++){
        float v = fmaxf(acc[m][n][jj] + bcol[n], 0.f);
        s += v; q += v*v;
      }
      #pragma unroll
      for (int off=1; off<16; off<<=1){ s += __shfl_xor(s, off); q += __shfl_xor(q, off); }
      if (lo == 0){ int r = m*16 + hi*4 + jj; sred[r*4+wave] = s; sred2[r*4+wave] = q; }
    }
  }
  __syncthreads();
  if (tid < 128){
    float ss=0.f, qq=0.f;
    #pragma unroll
    for (int w2=0; w2<4; w2++){ ss += sred[tid*4+w2]; qq += sred2[tid*4+w2]; }
    float mean = ss * (1.f/FILT);
    float var  = qq * (1.f/FILT) - mean*mean;
    smean[tid] = mean;
    srstd[tid] = rsqrtf(fmaxf(var, 0.f) + EPS);
  }
  __syncthreads();

  #pragma unroll
  for (int m=0;m<8;m++){
    int rbase = m*16 + hi*4;
    int p0v = pidT[rbase], p3v = pidT[rbase+3];
    int fold = (p0v == p3v);
    float mn[4], rs[4];
    #pragma unroll
    for (int jj=0;jj<4;jj++){ int r = rbase+jj; mn[jj]=smean[r]; rs[jj]=srstd[r]; }
    #pragma unroll
    for (int n=0;n<4;n++){
      int c = wave*64 + n*16 + lo;
      float o[4];
      #pragma unroll
      for (int jj=0;jj<4;jj++){
        float v = fmaxf(acc[m][n][jj] + bcol[n], 0.f);
        o[jj] = (v - mn[jj])*rs[jj]*gcol[n] + btcol[n];
      }
      float s4 = fold ? (o[0]+o[1]+o[2]+o[3]) : 0.f;
      float sp = __shfl_xor(s4, 16);
      int   pp = __shfl_xor(p0v, 16);
      int   fp = __shfl_xor(fold, 16);
      float* base = ps + (size_t)b*P_*FILT;
      if (fold){
        if (p0v < P_){
          if (fp && pp == p0v){
            if ((hi & 1) == 0) atomicAdd(base + (size_t)p0v*FILT + c, s4 + sp);
          } else {
            atomicAdd(base + (size_t)p0v*FILT + c, s4);
          }
        }
      } else {
        #pragma unroll
        for (int jj=0;jj<4;jj++){
          int pj = pidT[rbase+jj];
          if (pj < P_) atomicAdd(base + (size_t)pj*FILT + c, o[jj]);
        }
      }
    }
  }
}

// ---------------- word pooling + MLP ----------------
__global__ void word_k(const float* __restrict__ ps, const int* __restrict__ dur,
                       const int* __restrict__ wcum, const int* __restrict__ wpl,
                       const float* __restrict__ w1, const float* __restrict__ b1,
                       const float* __restrict__ w2, const float* __restrict__ b2,
                       float* __restrict__ wemb){
  int b = blockIdx.y, w = blockIdx.x, tid = threadIdx.x;
  __shared__ float wv[FILT];
  __shared__ float h1[FILT];
  int p1 = wcum[b*W_ + w]; int p0 = (w == 0) ? 0 : wcum[b*W_ + w - 1];
  if (p1 > P_) p1 = P_;
  int len = wpl[b*W_ + w];
  float a = 0.f;
  for (int p = p0; p < p1; ++p){
    int d = dur[b*P_ + p]; d = d < 1 ? 1 : d;
    a += ps[((size_t)(b*P_ + p))*FILT + tid] / (float)d;
  }
  wv[tid] = a / (float)(len < 1 ? 1 : len);
  __syncthreads();
  float t = b1[tid];
  for (int i=0;i<FILT;i++) t += wv[i] * w1[i*FILT + tid];
  h1[tid] = fmaxf(t, 0.f);
  __syncthreads();
  if (tid < PDIM){
    float u = b2[tid];
    for (int i=0;i<FILT;i++) u += h1[i] * w2[i*PDIM + tid];
    wemb[((size_t)(b*W_ + w))*PDIM + tid] = fmaxf(u, 0.f);
  }
}

// ---------------- expand words -> phones + mask ----------------
__global__ void expand_k(const float* __restrict__ wemb, const int* __restrict__ wid,
                         const unsigned char* __restrict__ mask, float* __restrict__ out){
  int idx = blockIdx.x * 256 + threadIdx.x;
  if (idx >= B_*P_*PDIM) return;
  int c = idx & 63; int p = (idx >> 6) & 511; int b = idx >> 15;
  int w = wid[b*P_ + p];
  float v = wemb[((size_t)(b*W_ + w))*PDIM + c];
  if (mask[b*P_ + p]) v = 0.f;
  out[idx] = v;
}

extern "C" void kernel_launch(void* const* d_in, const int* in_sizes, int n_in,
                              void* d_out, int out_size, void* d_ws, size_t ws_size,
                              hipStream_t stream) {
  const unsigned char* mask = (const unsigned char*)d_in[0];
  const float* mels = (const float*)d_in[1];
  const int*   dur  = (const int*)d_in[3];
  const int*   wpl  = (const int*)d_in[4];
  const float* c1w  = (const float*)d_in[5];
  const float* c1b  = (const float*)d_in[6];
  const float* l1g  = (const float*)d_in[7];
  const float* l1b  = (const float*)d_in[8];
  const float* c2w  = (const float*)d_in[9];
  const float* c2b  = (const float*)d_in[10];
  const float* l2g  = (const float*)d_in[11];
  const float* l2b  = (const float*)d_in[12];
  const float* w1   = (const float*)d_in[13];
  const float* b1   = (const float*)d_in[14];
  const float* w2   = (const float*)d_in[15];
  const float* b2   = (const float*)d_in[16];

  char* ws = (char*)d_ws;
  size_t off = 0;
  auto alloc = [&](size_t bytes){ void* p = ws + off; off += (bytes + 255) & ~(size_t)255; return p; };
  u16* melsPad = (u16*)alloc((size_t)B_*TP8*MSTR*2 + 4096);
  u16* y1Pad   = (u16*)alloc((size_t)B_*TP8*YSTR*2 + 4096);
  u16* Wp1     = (u16*)alloc((size_t)KW*12*FILT*8*2);
  u16* Wp2     = (u16*)alloc((size_t)KW*32*FILT*8*2 + 4096);
  int* dcum    = (int*)alloc((size_t)B_*P_*4);
  int* wcum    = (int*)alloc((size_t)B_*W_*4);
  int* pid     = (int*)alloc((size_t)B_*T_*4);
  int* wid     = (int*)alloc((size_t)B_*P_*4);
  float* psum  = (float*)alloc((size_t)B_*P_*FILT*4);
  float* wemb  = (float*)alloc((size_t)B_*W_*PDIM*4);

  hipMemsetAsync(psum, 0, (size_t)B_*P_*FILT*4, stream);
  pack_w<<<(KW*12*FILT + KW*32*FILT + 255)/256, 256, 0, stream>>>(c1w, c2w, Wp1, Wp2);
  prep_mels<<<(B_*TP8*MSTR + 255)/256, 256, 0, stream>>>(mels, melsPad);
  prep_seg<<<B_, 256, 0, stream>>>(dur, wpl, dcum, wcum, pid, wid, y1Pad);
  conv1_k<<<dim3(T_/128, B_), 256, 0, stream>>>(melsPad, Wp1, c1b, l1g, l1b, y1Pad);
  conv2_k<<<dim3(T_/128, B_), 256, 0, stream>>>(y1Pad, Wp2, c2b, l2g, l2b, pid, psum);
  word_k<<<dim3(W_, B_), 256, 0, stream>>>(psum, dur, wcum, wpl, w1, b1, w2, b2, wemb);
  expand_k<<<(B_*P_*PDIM + 255)/256, 256, 0, stream>>>(wemb, wid, mask, (float*)d_out);
}

// Round 2
// 355.480 us; speedup vs baseline: 1.0582x; 1.0582x over previous
//
#include <hip/hip_runtime.h>
#include <hip/hip_fp16.h>
#include <stdint.h>

#define B_ 32
#define T_ 4096
#define P_ 512
#define W_ 128
#define NMEL 80
#define FILT 256
#define PDIM 64
#define KW 9
#define TP8 (T_ + 8)
#define MSTR 104
#define YSTR 264
#define EPS 1e-5f

typedef unsigned short u16;
typedef __attribute__((ext_vector_type(8))) short short8;
typedef __attribute__((ext_vector_type(4))) float f32x4;

typedef const __attribute__((address_space(1))) uint32_t* gptr_t;
typedef __attribute__((address_space(3))) uint32_t* lptr_t;

__device__ __forceinline__ u16 f2h(float v){ return __half_as_ushort(__float2half(v)); }

#define MFMA16(accv, av, bv) \
  asm volatile("v_mfma_f32_16x16x32_f16 %0, %1, %2, %0" : "+v"(accv) : "v"(av), "v"(bv))

// ---------------- prep: pack conv weights to [tap][kg][cout][8] fp16 ----------------
__global__ void pack_w(const float* __restrict__ w1, const float* __restrict__ w2,
                       u16* __restrict__ Wp1, u16* __restrict__ Wp2){
  int i = blockIdx.x * 256 + threadIdx.x;
  const int N1 = KW * 12 * FILT;          // 27648
  const int N2 = KW * 32 * FILT;          // 73728
  if (i < N1){
    int tap = i / (12*FILT); int r = i - tap*12*FILT; int kg = r / FILT; int co = r - kg*FILT;
    short8 v;
    #pragma unroll
    for (int e=0;e<8;e++){
      int ci = kg*8 + e;
      float x = (ci < NMEL) ? w1[(co*NMEL + ci)*KW + tap] : 0.f;
      v[e] = (short)f2h(x);
    }
    *(short8*)(Wp1 + (size_t)i*8) = v;
  } else if (i < N1 + N2){
    int j = i - N1;
    int tap = j / (32*FILT); int r = j - tap*32*FILT; int kg = r / FILT; int co = r - kg*FILT;
    short8 v;
    #pragma unroll
    for (int e=0;e<8;e++){
      int ci = kg*8 + e;
      v[e] = (short)f2h(w2[(co*FILT + ci)*KW + tap]);
    }
    *(short8*)(Wp2 + (size_t)j*8) = v;
  }
}

// ---------------- prep: mels -> padded fp16 [B][T+8][104] ----------------
__global__ void prep_mels(const float* __restrict__ mels, u16* __restrict__ melsPad){
  int idx = blockIdx.x * 256 + threadIdx.x;
  if (idx >= B_*TP8*MSTR) return;
  int c = idx % MSTR; int r = idx / MSTR; int row = r % TP8; int b = r / TP8;
  float v = 0.f;
  int t = row - 4;
  if (t >= 0 && t < T_ && c < NMEL) v = mels[((size_t)b*T_ + t)*NMEL + c];
  melsPad[idx] = f2h(v);
}

// ---------------- prep: cumsums, frame->phone, phone->word, zero y1 halos ----------------
__global__ void prep_seg(const int* __restrict__ dur, const int* __restrict__ wpl,
                         int* __restrict__ dcum, int* __restrict__ wcum,
                         int* __restrict__ pid, int* __restrict__ wid,
                         u16* __restrict__ y1Pad){
  int b = blockIdx.x; int tid = threadIdx.x;
  __shared__ int dc[P_];
  __shared__ int wc[W_];
  if (tid == 0){ int run=0; for (int p=0;p<P_;p++){ run += dur[b*P_+p]; dc[p]=run; dcum[b*P_+p]=run; } }
  if (tid == 1){ int run=0; for (int w=0;w<W_;w++){ run += wpl[b*W_+w]; wc[w]=run; wcum[b*W_+w]=run; } }
  __syncthreads();
  for (int t=tid; t<T_; t+=256){
    int lo=0, hi=P_;
    while (lo < hi){ int mid=(lo+hi)>>1; if (dc[mid] > t) hi=mid; else lo=mid+1; }
    pid[b*T_+t] = lo;                 // may be P_ if t beyond total (dropped later)
  }
  for (int p=tid; p<P_; p+=256){
    int lo=0, hi=W_;
    while (lo < hi){ int mid=(lo+hi)>>1; if (wc[mid] > p) hi=mid; else lo=mid+1; }
    wid[b*P_+p] = min(lo, W_-1);
  }
  for (int i=tid; i<8*YSTR; i+=256){
    int rr = i / YSTR; int cc = i - rr*YSTR;
    int row = (rr < 4) ? rr : (T_ + rr);   // rows 0..3 and T_+4..T_+7
    y1Pad[((size_t)b*TP8 + row)*YSTR + cc] = 0;
  }
}

// ---------------- conv1 + bias + relu + LN1 -> y1Pad fp16 ----------------
// 256 threads, 4 waves (each: 128 rows x 64 couts). Double-buffered weight
// chunks (1 K-step = 4 kgroups = 16 KB), staged BEFORE compute of current
// chunk, single __syncthreads per chunk. LDS ~61 KB -> 2 blocks/CU.
__global__ __launch_bounds__(256, 2) void conv1_k(
    const u16* __restrict__ melsPad, const u16* __restrict__ Wp1,
    const float* __restrict__ bias, const float* __restrict__ lng,
    const float* __restrict__ lnb, u16* __restrict__ y1Pad){
  __shared__ __align__(16) u16 sA[14336];      // 28,672 B: >=136 rows x 104
  __shared__ __align__(16) u16 sB[2][8192];    // 2 x 16,384 B weight chunks
  const int tid = threadIdx.x;
  const int wave = tid >> 6, lane = tid & 63, lo = lane & 15, hi = lane >> 4;
  const int b = blockIdx.y, t0 = blockIdx.x * 128;

  {
    const char* gA = (const char*)(melsPad + ((size_t)b*TP8 + t0)*MSTR);
    #pragma unroll
    for (int it=0; it<7; ++it)
      __builtin_amdgcn_global_load_lds((gptr_t)(gA + it*4096 + tid*16),
                                       (lptr_t)((char*)sA + it*4096 + (wave<<10)), 16, 0, 0);
  }
  {
    const char* gW = (const char*)Wp1;   // chunk 0 = tap0, s0
    #pragma unroll
    for (int it=0; it<4; ++it)
      __builtin_amdgcn_global_load_lds((gptr_t)(gW + it*4096 + tid*16),
                                       (lptr_t)((char*)sB[0] + it*4096 + (wave<<10)), 16, 0, 0);
  }

  f32x4 acc[8][4];
  #pragma unroll
  for (int m=0;m<8;m++)
    #pragma unroll
    for (int n=0;n<4;n++) acc[m][n] = (f32x4){0.f,0.f,0.f,0.f};

  __syncthreads();
  for (int cc=0; cc<27; ++cc){
    if (cc < 26){
      int nx = cc + 1;
      const char* gW = (const char*)(Wp1 + (size_t)((nx/3)*12 + (nx%3)*4)*FILT*8);
      char* ldsB = (char*)sB[nx & 1];
      #pragma unroll
      for (int it=0; it<4; ++it)
        __builtin_amdgcn_global_load_lds((gptr_t)(gW + it*4096 + tid*16),
                                         (lptr_t)(ldsB + it*4096 + (wave<<10)), 16, 0, 0);
    }
    const int tap = cc / 3, s = cc % 3;
    const u16* bufB = sB[cc & 1];
    short8 av[8], wv[4];
    #pragma unroll
    for (int m=0;m<8;m++)
      av[m] = *(const short8*)(sA + (m*16 + lo + tap)*MSTR + s*32 + hi*8);
    #pragma unroll
    for (int n=0;n<4;n++)
      wv[n] = *(const short8*)(bufB + ((size_t)hi*FILT + wave*64 + n*16 + lo)*8);
    #pragma unroll
    for (int m=0;m<8;m++)
      #pragma unroll
      for (int n=0;n<4;n++)
        MFMA16(acc[m][n], av[m], wv[n]);
    __syncthreads();
  }
  asm volatile("s_nop 7\n\ts_nop 7" :: );

  float* sred  = (float*)sB;     // [128][4]
  float* sred2 = sred + 512;     // [128][4]
  float* smean = sred2 + 512;    // [128]
  float* srstd = smean + 128;    // [128]

  float bcol[4], gcol[4], btcol[4];
  #pragma unroll
  for (int n=0;n<4;n++){
    int c = wave*64 + n*16 + lo;
    bcol[n]=bias[c]; gcol[n]=lng[c]; btcol[n]=lnb[c];
  }
  #pragma unroll
  for (int m=0;m<8;m++){
    #pragma unroll
    for (int jj=0;jj<4;jj++){
      float s=0.f, q=0.f;
      #pragma unroll
      for (int n=0;n<4;n++){
        float v = fmaxf(acc[m][n][jj] + bcol[n], 0.f);
        s += v; q += v*v;
      }
      #pragma unroll
      for (int off=1; off<16; off<<=1){ s += __shfl_xor(s, off); q += __shfl_xor(q, off); }
      if (lo == 0){ int r = m*16 + hi*4 + jj; sred[r*4+wave] = s; sred2[r*4+wave] = q; }
    }
  }
  __syncthreads();
  if (tid < 128){
    float ss=0.f, qq=0.f;
    #pragma unroll
    for (int w2=0; w2<4; w2++){ ss += sred[tid*4+w2]; qq += sred2[tid*4+w2]; }
    float mean = ss * (1.f/FILT);
    float var  = qq * (1.f/FILT) - mean*mean;
    smean[tid] = mean;
    srstd[tid] = rsqrtf(fmaxf(var, 0.f) + EPS);
  }
  __syncthreads();
  #pragma unroll
  for (int m=0;m<8;m++){
    float mn[4], rs[4];
    #pragma unroll
    for (int jj=0;jj<4;jj++){ int r = m*16+hi*4+jj; mn[jj]=smean[r]; rs[jj]=srstd[r]; }
    #pragma unroll
    for (int jj=0;jj<4;jj++){
      int r = m*16 + hi*4 + jj;
      #pragma unroll
      for (int n=0;n<4;n++){
        float v = fmaxf(acc[m][n][jj] + bcol[n], 0.f);
        float o = (v - mn[jj])*rs[jj]*gcol[n] + btcol[n];
        y1Pad[((size_t)b*TP8 + 4 + t0 + r)*YSTR + wave*64 + n*16 + lo] = f2h(o);
      }
    }
  }
}

// ---------------- conv2 + bias + relu + LN2 -> phone-sum atomics ----------------
// 512 threads, 8 waves (2 row-groups x 4 col-groups; each wave 64 rows x 64
// couts, acc[4][4]). Double-buffered 32 KB weight chunks (2 K-steps),
// stage-at-top, one __syncthreads per chunk. LDS ~138 KB -> 1 block/CU,
// 8 waves = 2 waves/SIMD.
__global__ __launch_bounds__(512, 2) void conv2_k(
    const u16* __restrict__ y1Pad, const u16* __restrict__ Wp2,
    const float* __restrict__ bias, const float* __restrict__ lng,
    const float* __restrict__ lnb, const int* __restrict__ pid,
    float* __restrict__ ps){
  __shared__ __align__(16) u16 sA[36864];       // 73,728 B: >=136 rows x 264
  __shared__ __align__(16) u16 sB[2][16384];    // 2 x 32,768 B weight chunks
  __shared__ int pidT[128];
  const int tid = threadIdx.x;
  const int wave = tid >> 6, lane = tid & 63, lo = lane & 15, hi = lane >> 4;
  const int wr = wave >> 2, wc = wave & 3;
  const int b = blockIdx.y, t0 = blockIdx.x * 128;

  if (tid < 128) pidT[tid] = pid[b*T_ + t0 + tid];
  {
    const char* gA = (const char*)(y1Pad + ((size_t)b*TP8 + t0)*YSTR);
    #pragma unroll
    for (int it=0; it<9; ++it)
      __builtin_amdgcn_global_load_lds((gptr_t)(gA + it*8192 + tid*16),
                                       (lptr_t)((char*)sA + it*8192 + (wave<<10)), 16, 0, 0);
  }
  {
    const char* gW = (const char*)Wp2;   // chunk 0 = tap0, sblk0
    #pragma unroll
    for (int it=0; it<4; ++it)
      __builtin_amdgcn_global_load_lds((gptr_t)(gW + it*8192 + tid*16),
                                       (lptr_t)((char*)sB[0] + it*8192 + (wave<<10)), 16, 0, 0);
  }

  f32x4 acc[4][4];
  #pragma unroll
  for (int m=0;m<4;m++)
    #pragma unroll
    for (int n=0;n<4;n++) acc[m][n] = (f32x4){0.f,0.f,0.f,0.f};

  __syncthreads();
  for (int cc=0; cc<36; ++cc){
    if (cc < 35){
      int nx = cc + 1;
      const char* gW = (const char*)(Wp2 + (size_t)((nx>>2)*32 + (nx&3)*8)*FILT*8);
      char* ldsB = (char*)sB[nx & 1];
      #pragma unroll
      for (int it=0; it<4; ++it)
        __builtin_amdgcn_global_load_lds((gptr_t)(gW + it*8192 + tid*16),
                                         (lptr_t)(ldsB + it*8192 + (wave<<10)), 16, 0, 0);
    }
    const int tap = cc >> 2, sblk = cc & 3;
    const u16* bufB = sB[cc & 1];
    #pragma unroll
    for (int s2=0; s2<2; ++s2){
      const int sg = sblk*2 + s2;       // global K-step 0..7 (channels sg*32..)
      short8 av[4], wv[4];
      #pragma unroll
      for (int m=0;m<4;m++)
        av[m] = *(const short8*)(sA + (wr*64 + m*16 + lo + tap)*YSTR + sg*32 + hi*8);
      #pragma unroll
      for (int n=0;n<4;n++)
        wv[n] = *(const short8*)(bufB + ((size_t)(s2*4 + hi)*FILT + wc*64 + n*16 + lo)*8);
      #pragma unroll
      for (int m=0;m<4;m++)
        #pragma unroll
        for (int n=0;n<4;n++)
          MFMA16(acc[m][n], av[m], wv[n]);
    }
    __syncthreads();
  }
  asm volatile("s_nop 7\n\ts_nop 7" :: );

  float* sred  = (float*)sA;     // [128][4]
  float* sred2 = sred + 512;     // [128][4]
  float* smean = sred2 + 512;    // [128]
  float* srstd = smean + 128;    // [128]

  float bcol[4], gcol[4], btcol[4];
  #pragma unroll
  for (int n=0;n<4;n++){
    int c = wc*64 + n*16 + lo;
    bcol[n]=bias[c]; gcol[n]=lng[c]; btcol[n]=lnb[c];
  }
  #pragma unroll
  for (int m=0;m<4;m++){
    #pragma unroll
    for (int jj=0;jj<4;jj++){
      float s=0.f, q=0.f;
      #pragma unroll
      for (int n=0;n<4;n++){
        float v = fmaxf(acc[m][n][jj] + bcol[n], 0.f);
        s += v; q += v*v;
      }
      #pragma unroll
      for (int off=1; off<16; off<<=1){ s += __shfl_xor(s, off); q += __shfl_xor(q, off); }
      if (lo == 0){ int r = wr*64 + m*16 + hi*4 + jj; sred[r*4+wc] = s; sred2[r*4+wc] = q; }
    }
  }
  __syncthreads();
  if (tid < 128){
    float ss=0.f, qq=0.f;
    #pragma unroll
    for (int w2=0; w2<4; w2++){ ss += sred[tid*4+w2]; qq += sred2[tid*4+w2]; }
    float mean = ss * (1.f/FILT);
    float var  = qq * (1.f/FILT) - mean*mean;
    smean[tid] = mean;
    srstd[tid] = rsqrtf(fmaxf(var, 0.f) + EPS);
  }
  __syncthreads();

  #pragma unroll
  for (int m=0;m<4;m++){
    int rbase = wr*64 + m*16 + hi*4;
    int p0v = pidT[rbase], p3v = pidT[rbase+3];
    int fold = (p0v == p3v);
    float mn[4], rs[4];
    #pragma unroll
    for (int jj=0;jj<4;jj++){ int r = rbase+jj; mn[jj]=smean[r]; rs[jj]=srstd[r]; }
    #pragma unroll
    for (int n=0;n<4;n++){
      int c = wc*64 + n*16 + lo;
      float o[4];
      #pragma unroll
      for (int jj=0;jj<4;jj++){
        float v = fmaxf(acc[m][n][jj] + bcol[n], 0.f);
        o[jj] = (v - mn[jj])*rs[jj]*gcol[n] + btcol[n];
      }
      float s4 = fold ? (o[0]+o[1]+o[2]+o[3]) : 0.f;
      float sp = __shfl_xor(s4, 16);
      int   pp = __shfl_xor(p0v, 16);
      int   fp = __shfl_xor(fold, 16);
      float* base = ps + (size_t)b*P_*FILT;
      if (fold){
        if (p0v < P_){
          if (fp && pp == p0v){
            if ((hi & 1) == 0) atomicAdd(base + (size_t)p0v*FILT + c, s4 + sp);
          } else {
            atomicAdd(base + (size_t)p0v*FILT + c, s4);
          }
        }
      } else {
        #pragma unroll
        for (int jj=0;jj<4;jj++){
          int pj = pidT[rbase+jj];
          if (pj < P_) atomicAdd(base + (size_t)pj*FILT + c, o[jj]);
        }
      }
    }
  }
}

// ---------------- word pooling + MLP: 8 words per block ----------------
#define WPB 8
__global__ __launch_bounds__(256) void word_k(
    const float* __restrict__ ps, const int* __restrict__ dur,
    const int* __restrict__ wcum, const int* __restrict__ wpl,
    const float* __restrict__ w1, const float* __restrict__ b1,
    const float* __restrict__ w2, const float* __restrict__ b2,
    float* __restrict__ wemb){
  int b = blockIdx.y, wg = blockIdx.x * WPB, tid = threadIdx.x;
  __shared__ float wvS[WPB][FILT];
  __shared__ float h1S[WPB][FILT];
  #pragma unroll
  for (int k=0;k<WPB;k++){
    int w = wg + k;
    int p1 = wcum[b*W_ + w]; int p0 = (w == 0) ? 0 : wcum[b*W_ + w - 1];
    if (p1 > P_) p1 = P_;
    int len = wpl[b*W_ + w];
    float a = 0.f;
    for (int p = p0; p < p1; ++p){
      int d = dur[b*P_ + p]; d = d < 1 ? 1 : d;
      a += ps[((size_t)(b*P_ + p))*FILT + tid] / (float)d;
    }
    wvS[k][tid] = a / (float)(len < 1 ? 1 : len);
  }
  __syncthreads();
  float acc[WPB];
  #pragma unroll
  for (int k=0;k<WPB;k++) acc[k] = b1[tid];
  for (int i=0;i<FILT;i++){
    float wcol = w1[i*FILT + tid];
    #pragma unroll
    for (int k=0;k<WPB;k++) acc[k] += wvS[k][i] * wcol;
  }
  #pragma unroll
  for (int k=0;k<WPB;k++) h1S[k][tid] = fmaxf(acc[k], 0.f);
  __syncthreads();
  int c = tid & 63, kq = tid >> 6;     // 4 thread-groups of 64
  #pragma unroll
  for (int kk=kq; kk<WPB; kk+=4){
    float u = b2[c];
    for (int i=0;i<FILT;i++) u += h1S[kk][i] * w2[i*PDIM + c];
    wemb[((size_t)(b*W_ + wg + kk))*PDIM + c] = fmaxf(u, 0.f);
  }
}

// ---------------- expand words -> phones + mask ----------------
__global__ void expand_k(const float* __restrict__ wemb, const int* __restrict__ wid,
                         const unsigned char* __restrict__ mask, float* __restrict__ out){
  int idx = blockIdx.x * 256 + threadIdx.x;
  if (idx >= B_*P_*PDIM) return;
  int c = idx & 63; int p = (idx >> 6) & 511; int b = idx >> 15;
  int w = wid[b*P_ + p];
  float v = wemb[((size_t)(b*W_ + w))*PDIM + c];
  if (mask[b*P_ + p]) v = 0.f;
  out[idx] = v;
}

extern "C" void kernel_launch(void* const* d_in, const int* in_sizes, int n_in,
                              void* d_out, int out_size, void* d_ws, size_t ws_size,
                              hipStream_t stream) {
  const unsigned char* mask = (const unsigned char*)d_in[0];
  const float* mels = (const float*)d_in[1];
  const int*   dur  = (const int*)d_in[3];
  const int*   wpl  = (const int*)d_in[4];
  const float* c1w  = (const float*)d_in[5];
  const float* c1b  = (const float*)d_in[6];
  const float* l1g  = (const float*)d_in[7];
  const float* l1b  = (const float*)d_in[8];
  const float* c2w  = (const float*)d_in[9];
  const float* c2b  = (const float*)d_in[10];
  const float* l2g  = (const float*)d_in[11];
  const float* l2b  = (const float*)d_in[12];
  const float* w1   = (const float*)d_in[13];
  const float* b1   = (const float*)d_in[14];
  const float* w2   = (const float*)d_in[15];
  const float* b2   = (const float*)d_in[16];

  char* ws = (char*)d_ws;
  size_t off = 0;
  auto alloc = [&](size_t bytes){ void* p = ws + off; off += (bytes + 255) & ~(size_t)255; return p; };
  u16* melsPad = (u16*)alloc((size_t)B_*TP8*MSTR*2 + 4096);
  u16* y1Pad   = (u16*)alloc((size_t)B_*TP8*YSTR*2 + 4096);
  u16* Wp1     = (u16*)alloc((size_t)KW*12*FILT*8*2);
  u16* Wp2     = (u16*)alloc((size_t)KW*32*FILT*8*2 + 4096);
  int* dcum    = (int*)alloc((size_t)B_*P_*4);
  int* wcum    = (int*)alloc((size_t)B_*W_*4);
  int* pid     = (int*)alloc((size_t)B_*T_*4);
  int* wid     = (int*)alloc((size_t)B_*P_*4);
  float* psum  = (float*)alloc((size_t)B_*P_*FILT*4);
  float* wemb  = (float*)alloc((size_t)B_*W_*PDIM*4);

  hipMemsetAsync(psum, 0, (size_t)B_*P_*FILT*4, stream);
  pack_w<<<(KW*12*FILT + KW*32*FILT + 255)/256, 256, 0, stream>>>(c1w, c2w, Wp1, Wp2);
  prep_mels<<<(B_*TP8*MSTR + 255)/256, 256, 0, stream>>>(mels, melsPad);
  prep_seg<<<B_, 256, 0, stream>>>(dur, wpl, dcum, wcum, pid, wid, y1Pad);
  conv1_k<<<dim3(T_/128, B_), 256, 0, stream>>>(melsPad, Wp1, c1b, l1g, l1b, y1Pad);
  conv2_k<<<dim3(T_/128, B_), 512, 0, stream>>>(y1Pad, Wp2, c2b, l2g, l2b, pid, psum);
  word_k<<<dim3(W_/WPB, B_), 256, 0, stream>>>(psum, dur, wcum, wpl, w1, b1, w2, b2, wemb);
  expand_k<<<(B_*P_*PDIM + 255)/256, 256, 0, stream>>>(wemb, wid, mask, (float*)d_out);
}